// Round 1
// baseline (391.717 us; speedup 1.0000x reference)
//
#include <hip/hip_runtime.h>
#include <hip/hip_bf16.h>
#include <math.h>

typedef __hip_bfloat16 bf16;
typedef __attribute__((ext_vector_type(8))) short short8;   // 8 bf16 = 4 VGPRs (guide §3)
typedef __attribute__((ext_vector_type(4))) float f32x4;

#define DEV __device__ __forceinline__

// problem constants
constexpr int CB = 8, CN = 1024, CD = 768, CH = 12, CK = 64, CF = 3072;
constexpr int ROWS = CB * CN;  // 8192

// ---------------------------------------------------------------- utilities
DEV void gload_lds16(const void* g, void* l) {
  // async global->LDS, 16B per lane; LDS dest = wave-uniform base + lane*16
  __builtin_amdgcn_global_load_lds(
      (const __attribute__((address_space(1))) void*)g,
      (__attribute__((address_space(3))) void*)l, 16, 0, 0);
}

// ------------------------------------------------------- weight prep (T + cast)
// in[R][C] fp32  ->  out[C][R] bf16
__global__ __launch_bounds__(256) void transpose_f32_bf16(
    const float* __restrict__ in, bf16* __restrict__ out, int R, int C) {
  __shared__ float tile[32][33];
  const int tx = threadIdx.x & 31, ty = threadIdx.x >> 5;  // 32 x 8
  const int c0 = blockIdx.x * 32, r0 = blockIdx.y * 32;
#pragma unroll
  for (int i = 0; i < 4; ++i)
    tile[ty + i * 8][tx] = in[(size_t)(r0 + ty + i * 8) * C + c0 + tx];
  __syncthreads();
#pragma unroll
  for (int i = 0; i < 4; ++i)
    out[(size_t)(c0 + ty + i * 8) * R + r0 + tx] =
        __float2bfloat16(tile[tx][ty + i * 8]);
}

// ---------------------------------------------------------------- LayerNorm
__global__ __launch_bounds__(256) void ln_bf16(
    const float* __restrict__ in, const float* __restrict__ gamma,
    const float* __restrict__ beta, bf16* __restrict__ out) {
  const int row = blockIdx.x;
  const int tid = threadIdx.x;
  const float* x = in + (size_t)row * CD;
  const float v0 = x[tid], v1 = x[tid + 256], v2 = x[tid + 512];
  float s = v0 + v1 + v2;
  float q = v0 * v0 + v1 * v1 + v2 * v2;
#pragma unroll
  for (int off = 32; off > 0; off >>= 1) {
    s += __shfl_xor(s, off);
    q += __shfl_xor(q, off);
  }
  __shared__ float sm[8];
  const int w = tid >> 6, l = tid & 63;
  if (l == 0) { sm[w] = s; sm[4 + w] = q; }
  __syncthreads();
  s = sm[0] + sm[1] + sm[2] + sm[3];
  q = sm[4] + sm[5] + sm[6] + sm[7];
  const float mean = s * (1.f / CD);
  const float var = q * (1.f / CD) - mean * mean;
  const float rs = rsqrtf(var + 1e-5f);
  bf16* o = out + (size_t)row * CD;
  o[tid]       = __float2bfloat16((v0 - mean) * rs * gamma[tid]       + beta[tid]);
  o[tid + 256] = __float2bfloat16((v1 - mean) * rs * gamma[tid + 256] + beta[tid + 256]);
  o[tid + 512] = __float2bfloat16((v2 - mean) * rs * gamma[tid + 512] + beta[tid + 512]);
}

// ---------------------------------------------------------------- GEMM
// C[M,N] = A[M,K] * Bt[N,K]^T  (both bf16, fp32 accum), 128x128 tile, BK=32,
// 4 waves (2x2), each wave 64x64 via 4x4 mfma_f32_16x16x32_bf16 fragments.
// EPI: 0 = QKV scatter (+bias, bf16 [B,H,N,K]); 1 = +bias +resid, fp32 out (ld=CD);
//      2 = +bias, exact GELU, bf16 out (ld=CF).
template <int EPI>
__global__ __launch_bounds__(256) void gemm_bf16_kernel(
    const bf16* __restrict__ A, const bf16* __restrict__ Bt, int Kd,
    float* __restrict__ outF, bf16* __restrict__ dst0, bf16* __restrict__ dst1,
    bf16* __restrict__ dst2, const float* __restrict__ bias0,
    const float* __restrict__ bias1, const float* __restrict__ bias2,
    const float* __restrict__ resid) {
  __shared__ __align__(16) bf16 As[128 * 32];
  __shared__ __align__(16) bf16 Bs[128 * 32];
  const int tid = threadIdx.x;
  const int w = tid >> 6, l = tid & 63;
  const int wr = w >> 1, wc = w & 1;
  const int l15 = l & 15, lg = l >> 4;
  const int rowBase = blockIdx.y * 128;
  const int colBase = blockIdx.x * 128;

  f32x4 acc[4][4];
#pragma unroll
  for (int i = 0; i < 4; ++i)
#pragma unroll
    for (int j = 0; j < 4; ++j)
#pragma unroll
      for (int r = 0; r < 4; ++r) acc[i][j][r] = 0.f;

  for (int k0 = 0; k0 < Kd; k0 += 32) {
    __syncthreads();
#pragma unroll
    for (int i = 0; i < 2; ++i) {
      const int c = w * 128 + i * 64 + l;       // 16B chunk id, 0..511
      const int r = c >> 2, cc = c & 3;         // tile row, 8-elem col chunk
      gload_lds16(A + (size_t)(rowBase + r) * Kd + k0 + cc * 8,
                  (void*)&As[(w * 128 + i * 64) * 8]);
      gload_lds16(Bt + (size_t)(colBase + r) * Kd + k0 + cc * 8,
                  (void*)&Bs[(w * 128 + i * 64) * 8]);
    }
    __syncthreads();
    short8 af[4], bfr[4];
#pragma unroll
    for (int fm = 0; fm < 4; ++fm)
      af[fm] = *reinterpret_cast<const short8*>(
          &As[(wr * 64 + fm * 16 + l15) * 32 + lg * 8]);
#pragma unroll
    for (int fn = 0; fn < 4; ++fn)
      bfr[fn] = *reinterpret_cast<const short8*>(
          &Bs[(wc * 64 + fn * 16 + l15) * 32 + lg * 8]);
#pragma unroll
    for (int fm = 0; fm < 4; ++fm)
#pragma unroll
      for (int fn = 0; fn < 4; ++fn)
        acc[fm][fn] = __builtin_amdgcn_mfma_f32_16x16x32_bf16(
            af[fm], bfr[fn], acc[fm][fn], 0, 0, 0);
  }

  // epilogue: C row = rowBase+wr*64+fm*16+lg*4+fr ; col = colBase+wc*64+fn*16+l15
  const int mrow0 = rowBase + wr * 64;
  const int ncol0 = colBase + wc * 64;
#pragma unroll
  for (int fm = 0; fm < 4; ++fm) {
#pragma unroll
    for (int fn = 0; fn < 4; ++fn) {
      const int col = ncol0 + fn * 16 + l15;
#pragma unroll
      for (int fr = 0; fr < 4; ++fr) {
        const int row = mrow0 + fm * 16 + lg * 4 + fr;
        float v = acc[fm][fn][fr];
        if constexpr (EPI == 0) {
          const int which = col / CD;  // 0=q 1=k 2=v (block never straddles)
          const int hk = col - which * CD;
          const float* bias = (which == 0) ? bias0 : (which == 1) ? bias1 : bias2;
          bf16* dst = (which == 0) ? dst0 : (which == 1) ? dst1 : dst2;
          v += bias[hk];
          const int b = row >> 10, n = row & 1023;
          const int h = hk >> 6, kk = hk & 63;
          dst[(((size_t)(b * CH + h)) * CN + n) * CK + kk] = __float2bfloat16(v);
        } else if constexpr (EPI == 1) {
          v += bias0[col] + resid[(size_t)row * CD + col];
          outF[(size_t)row * CD + col] = v;
        } else {  // EPI == 2: exact GELU -> bf16, ld = CF
          v += bias0[col];
          const float gel = 0.5f * v * (1.0f + erff(v * 0.70710678118654752f));
          dst0[(size_t)row * CF + col] = __float2bfloat16(gel);
        }
      }
    }
  }
}

// ---------------------------------------------------------------- attention
// Flash-style. grid = B*H*16; block = 256 (4 waves), wave w owns 16 q-rows.
// Q/K/V bf16 [B,H,N,K]; ctx out bf16 [B,N,H*K] (= out-proj A layout).
__global__ __launch_bounds__(256) void attn_kernel(
    const bf16* __restrict__ Qb, const bf16* __restrict__ Kb,
    const bf16* __restrict__ Vb, bf16* __restrict__ ctxb) {
  __shared__ __align__(16) bf16 Qs[64][72];    // [q][k]   +8 pad: no 128B-stride conflict
  __shared__ __align__(16) bf16 Ks[64][72];    // [m][k]
  __shared__ __align__(16) bf16 Vts[64][72];   // [k][m]  (transposed for PV B-frag)
  __shared__ __align__(16) bf16 Ps[4][16][72]; // per-wave P tile [q][m]

  const int tid = threadIdx.x;
  const int w = tid >> 6, l = tid & 63;
  const int l15 = l & 15, lg = l >> 4;
  const int bx = blockIdx.x;
  const int bh = bx >> 4, qt = bx & 15;
  const int b = bh / CH, h = bh - b * CH;
  const size_t headBase = (size_t)bh * CN * CK;

  {  // stage Q (64 rows x 64)
    const bf16* src = Qb + headBase + (size_t)qt * 64 * CK;
#pragma unroll
    for (int i = 0; i < 2; ++i) {
      const int c = i * 256 + tid;
      const int r = c >> 3, cc = c & 7;
      uint4 v = *reinterpret_cast<const uint4*>(src + r * CK + cc * 8);
      *reinterpret_cast<uint4*>(&Qs[r][cc * 8]) = v;
    }
  }
  __syncthreads();
  const short8 aq0 = *reinterpret_cast<const short8*>(&Qs[w * 16 + l15][lg * 8]);
  const short8 aq1 = *reinterpret_cast<const short8*>(&Qs[w * 16 + l15][32 + lg * 8]);

  f32x4 oacc[4];
  float mold[4], lsum[4];
#pragma unroll
  for (int r = 0; r < 4; ++r) {
    mold[r] = -INFINITY;
    lsum[r] = 0.f;
#pragma unroll
    for (int kb = 0; kb < 4; ++kb) oacc[kb][r] = 0.f;
  }

  for (int kt = 0; kt < 16; ++kt) {
    __syncthreads();
    {  // stage K row-major, V transposed
      const bf16* ksrc = Kb + headBase + (size_t)kt * 64 * CK;
      const bf16* vsrc = Vb + headBase + (size_t)kt * 64 * CK;
#pragma unroll
      for (int i = 0; i < 2; ++i) {
        const int c = i * 256 + tid;
        const int r = c >> 3, cc = c & 7;
        uint4 kv = *reinterpret_cast<const uint4*>(ksrc + r * CK + cc * 8);
        *reinterpret_cast<uint4*>(&Ks[r][cc * 8]) = kv;
        uint4 vv = *reinterpret_cast<const uint4*>(vsrc + r * CK + cc * 8);
        const bf16* e = reinterpret_cast<const bf16*>(&vv);
#pragma unroll
        for (int j = 0; j < 8; ++j) Vts[cc * 8 + j][r] = e[j];
      }
    }
    __syncthreads();

    // S = Q K^T / 8  (D[q][m]: col=lane&15=m_local, row=lg*4+reg=q_local)
    f32x4 sacc[4];
#pragma unroll
    for (int mb = 0; mb < 4; ++mb) {
      const short8 b0 = *reinterpret_cast<const short8*>(&Ks[mb * 16 + l15][lg * 8]);
      const short8 b1 = *reinterpret_cast<const short8*>(&Ks[mb * 16 + l15][32 + lg * 8]);
      f32x4 z;
#pragma unroll
      for (int r = 0; r < 4; ++r) z[r] = 0.f;
      z = __builtin_amdgcn_mfma_f32_16x16x32_bf16(aq0, b0, z, 0, 0, 0);
      z = __builtin_amdgcn_mfma_f32_16x16x32_bf16(aq1, b1, z, 0, 0, 0);
      sacc[mb] = z;
    }
#pragma unroll
    for (int mb = 0; mb < 4; ++mb) sacc[mb] *= 0.125f;

    // online softmax per q-row (row r of reg, 16-lane group reduce)
    float alpha[4];
#pragma unroll
    for (int r = 0; r < 4; ++r) {
      float mx = fmaxf(fmaxf(sacc[0][r], sacc[1][r]), fmaxf(sacc[2][r], sacc[3][r]));
#pragma unroll
      for (int off = 1; off < 16; off <<= 1) mx = fmaxf(mx, __shfl_xor(mx, off));
      const float mnew = fmaxf(mold[r], mx);
      alpha[r] = __expf(mold[r] - mnew);
      float rs = 0.f;
#pragma unroll
      for (int mb = 0; mb < 4; ++mb) {
        const float p = __expf(sacc[mb][r] - mnew);
        sacc[mb][r] = p;
        rs += p;
      }
#pragma unroll
      for (int off = 1; off < 16; off <<= 1) rs += __shfl_xor(rs, off);
      lsum[r] = lsum[r] * alpha[r] + rs;
      mold[r] = mnew;
    }

    // P -> LDS (per-wave; intra-wave DS ops are in-order, no barrier needed)
#pragma unroll
    for (int mb = 0; mb < 4; ++mb)
#pragma unroll
      for (int r = 0; r < 4; ++r)
        Ps[w][lg * 4 + r][mb * 16 + l15] = __float2bfloat16(sacc[mb][r]);

    const short8 pa0 = *reinterpret_cast<const short8*>(&Ps[w][l15][lg * 8]);
    const short8 pa1 = *reinterpret_cast<const short8*>(&Ps[w][l15][32 + lg * 8]);
#pragma unroll
    for (int kb = 0; kb < 4; ++kb) {
#pragma unroll
      for (int r = 0; r < 4; ++r) oacc[kb][r] *= alpha[r];
      const short8 vb0 = *reinterpret_cast<const short8*>(&Vts[kb * 16 + l15][lg * 8]);
      const short8 vb1 = *reinterpret_cast<const short8*>(&Vts[kb * 16 + l15][32 + lg * 8]);
      oacc[kb] = __builtin_amdgcn_mfma_f32_16x16x32_bf16(pa0, vb0, oacc[kb], 0, 0, 0);
      oacc[kb] = __builtin_amdgcn_mfma_f32_16x16x32_bf16(pa1, vb1, oacc[kb], 0, 0, 0);
    }
  }

  // finalize: ctx[b][n][h*64+k]
#pragma unroll
  for (int r = 0; r < 4; ++r) {
    const float inv = 1.f / lsum[r];
    const int n = qt * 64 + w * 16 + lg * 4 + r;
    bf16* dst = ctxb + ((size_t)(b * CN + n)) * CD + h * CK;
#pragma unroll
    for (int kb = 0; kb < 4; ++kb)
      dst[kb * 16 + l15] = __float2bfloat16(oacc[kb][r] * inv);
  }
}

// ---------------------------------------------------------------- launcher
// ws arena (bytes):
//   0         wqkvt  bf16 [2304][768]
//   3538944   wot    bf16 [768][768]
//   4718592   w1t    bf16 [3072][768]
//   9437184   w2t    bf16 [768][3072]
//   14155776  h1     bf16 [8192][768]   } reused as g bf16 [8192][3072]
//   26738688  Q      bf16 [B,H,N,K]     }   (50331648 B total, exact fit)
//   39321600  K                         }
//   51904512  V                         }
//   64487424  ctx    bf16 [8192][768]   -> reused as h2
//   77070336  out    f32  [8192][768]
//   total 102236160
extern "C" void kernel_launch(void* const* d_in, const int* in_sizes, int n_in,
                              void* d_out, int out_size, void* d_ws,
                              size_t ws_size, hipStream_t stream) {
  const float* x    = (const float*)d_in[0];
  const float* ln1g = (const float*)d_in[1];
  const float* ln1b = (const float*)d_in[2];
  const float* wq   = (const float*)d_in[3];
  const float* bq   = (const float*)d_in[4];
  const float* wk   = (const float*)d_in[5];
  const float* bk   = (const float*)d_in[6];
  const float* wv   = (const float*)d_in[7];
  const float* bv   = (const float*)d_in[8];
  const float* wo   = (const float*)d_in[9];
  const float* bo   = (const float*)d_in[10];
  const float* ln2g = (const float*)d_in[11];
  const float* ln2b = (const float*)d_in[12];
  const float* w1   = (const float*)d_in[13];
  const float* b1   = (const float*)d_in[14];
  const float* w2   = (const float*)d_in[15];
  const float* b2   = (const float*)d_in[16];

  char* ws = (char*)d_ws;
  bf16* wqkvt = (bf16*)(ws + 0);
  bf16* wot   = (bf16*)(ws + 3538944);
  bf16* w1t   = (bf16*)(ws + 4718592);
  bf16* w2t   = (bf16*)(ws + 9437184);
  bf16* h1    = (bf16*)(ws + 14155776);
  bf16* Qb    = (bf16*)(ws + 26738688);
  bf16* Kb    = (bf16*)(ws + 39321600);
  bf16* Vb    = (bf16*)(ws + 51904512);
  bf16* gb    = (bf16*)(ws + 14155776);  // reuse h1+Q+K+V region
  bf16* ctxb  = (bf16*)(ws + 64487424);
  bf16* h2    = (bf16*)(ws + 64487424);  // reuse ctx region
  float* outb = (float*)(ws + 77070336);
  float* y    = (float*)d_out;

  // weight prep: fp32 [R][C] -> bf16 [C][R]
  transpose_f32_bf16<<<dim3(24, 24), 256, 0, stream>>>(wq, wqkvt, 768, 768);
  transpose_f32_bf16<<<dim3(24, 24), 256, 0, stream>>>(wk, wqkvt + 768 * 768, 768, 768);
  transpose_f32_bf16<<<dim3(24, 24), 256, 0, stream>>>(wv, wqkvt + 2 * 768 * 768, 768, 768);
  transpose_f32_bf16<<<dim3(24, 24), 256, 0, stream>>>(wo, wot, 768, 768);
  transpose_f32_bf16<<<dim3(96, 24), 256, 0, stream>>>(w1, w1t, 768, 3072);
  transpose_f32_bf16<<<dim3(24, 96), 256, 0, stream>>>(w2, w2t, 3072, 768);

  ln_bf16<<<ROWS, 256, 0, stream>>>(x, ln1g, ln1b, h1);

  gemm_bf16_kernel<0><<<dim3(2304 / 128, ROWS / 128), 256, 0, stream>>>(
      h1, wqkvt, 768, nullptr, Qb, Kb, Vb, bq, bk, bv, nullptr);

  attn_kernel<<<CB * CH * 16, 256, 0, stream>>>(Qb, Kb, Vb, ctxb);

  gemm_bf16_kernel<1><<<dim3(768 / 128, ROWS / 128), 256, 0, stream>>>(
      ctxb, wot, 768, outb, nullptr, nullptr, nullptr, bo, nullptr, nullptr, x);

  ln_bf16<<<ROWS, 256, 0, stream>>>(outb, ln2g, ln2b, h2);

  gemm_bf16_kernel<2><<<dim3(3072 / 128, ROWS / 128), 256, 0, stream>>>(
      h2, w1t, 768, nullptr, gb, nullptr, nullptr, b1, nullptr, nullptr, nullptr);

  gemm_bf16_kernel<1><<<dim3(768 / 128, ROWS / 128), 256, 0, stream>>>(
      gb, w2t, 3072, y, nullptr, nullptr, nullptr, b2, nullptr, nullptr, outb);

  (void)in_sizes; (void)n_in; (void)out_size; (void)ws_size;
}

// Round 2
// 382.174 us; speedup vs baseline: 1.0250x; 1.0250x over previous
//
#include <hip/hip_runtime.h>
#include <hip/hip_bf16.h>
#include <math.h>

typedef __hip_bfloat16 bf16;
typedef __attribute__((ext_vector_type(8))) short short8;   // 8 bf16 = 4 VGPRs (guide §3)
typedef __attribute__((ext_vector_type(4))) float f32x4;

#define DEV __device__ __forceinline__

// problem constants
constexpr int CB = 8, CN = 1024, CD = 768, CH = 12, CK = 64, CF = 3072;
constexpr int ROWS = CB * CN;  // 8192

// ---------------------------------------------------------------- utilities
DEV void gload_lds16(const void* g, void* l) {
  __builtin_amdgcn_global_load_lds(
      (const __attribute__((address_space(1))) void*)g,
      (__attribute__((address_space(3))) void*)l, 16, 0, 0);
}

// ------------------------------------------------------- weight prep (T + cast)
// in[R][C] fp32  ->  out[C][R] bf16, optionally scaled
__global__ __launch_bounds__(256) void transpose_f32_bf16(
    const float* __restrict__ in, bf16* __restrict__ out, int R, int C,
    float scale) {
  __shared__ float tile[32][33];
  const int tx = threadIdx.x & 31, ty = threadIdx.x >> 5;  // 32 x 8
  const int c0 = blockIdx.x * 32, r0 = blockIdx.y * 32;
#pragma unroll
  for (int i = 0; i < 4; ++i)
    tile[ty + i * 8][tx] = in[(size_t)(r0 + ty + i * 8) * C + c0 + tx];
  __syncthreads();
#pragma unroll
  for (int i = 0; i < 4; ++i)
    out[(size_t)(c0 + ty + i * 8) * R + r0 + tx] =
        __float2bfloat16(tile[tx][ty + i * 8] * scale);
}

// ---------------------------------------------------------------- LayerNorm
__global__ __launch_bounds__(256) void ln_bf16(
    const float* __restrict__ in, const float* __restrict__ gamma,
    const float* __restrict__ beta, bf16* __restrict__ out) {
  const int row = blockIdx.x;
  const int tid = threadIdx.x;
  const float* x = in + (size_t)row * CD;
  const float v0 = x[tid], v1 = x[tid + 256], v2 = x[tid + 512];
  float s = v0 + v1 + v2;
  float q = v0 * v0 + v1 * v1 + v2 * v2;
#pragma unroll
  for (int off = 32; off > 0; off >>= 1) {
    s += __shfl_xor(s, off);
    q += __shfl_xor(q, off);
  }
  __shared__ float sm[8];
  const int w = tid >> 6, l = tid & 63;
  if (l == 0) { sm[w] = s; sm[4 + w] = q; }
  __syncthreads();
  s = sm[0] + sm[1] + sm[2] + sm[3];
  q = sm[4] + sm[5] + sm[6] + sm[7];
  const float mean = s * (1.f / CD);
  const float var = q * (1.f / CD) - mean * mean;
  const float rs = rsqrtf(var + 1e-5f);
  bf16* o = out + (size_t)row * CD;
  o[tid]       = __float2bfloat16((v0 - mean) * rs * gamma[tid]       + beta[tid]);
  o[tid + 256] = __float2bfloat16((v1 - mean) * rs * gamma[tid + 256] + beta[tid + 256]);
  o[tid + 512] = __float2bfloat16((v2 - mean) * rs * gamma[tid + 512] + beta[tid + 512]);
}

// ---------------------------------------------------------------- GEMM
// C[M,N] = A[M,K] * Bt[N,K]^T  (both bf16, fp32 accum), 128x128 tile, BK=32,
// 4 waves (2x2), each wave 64x64 via 4x4 mfma_f32_16x16x32_bf16 fragments.
// EPI: 0 = QKV scatter (+bias; Q/K -> [B,H,N,K], V -> [B,H,K,N] transposed;
//          wq/bq pre-scaled by 1/8 so attention needs no scale);
//      1 = +bias +resid, fp32 out (ld=CD); 2 = +bias, exact GELU, bf16 (ld=CF).
template <int EPI>
__global__ __launch_bounds__(256) void gemm_bf16_kernel(
    const bf16* __restrict__ A, const bf16* __restrict__ Bt, int Kd,
    float* __restrict__ outF, bf16* __restrict__ dst0, bf16* __restrict__ dst1,
    bf16* __restrict__ dst2, const float* __restrict__ bias0,
    const float* __restrict__ bias1, const float* __restrict__ bias2,
    const float* __restrict__ resid) {
  __shared__ __align__(16) bf16 As[128 * 32];
  __shared__ __align__(16) bf16 Bs[128 * 32];
  const int tid = threadIdx.x;
  const int w = tid >> 6, l = tid & 63;
  const int wr = w >> 1, wc = w & 1;
  const int l15 = l & 15, lg = l >> 4;
  const int rowBase = blockIdx.y * 128;
  const int colBase = blockIdx.x * 128;

  f32x4 acc[4][4];
#pragma unroll
  for (int i = 0; i < 4; ++i)
#pragma unroll
    for (int j = 0; j < 4; ++j)
#pragma unroll
      for (int r = 0; r < 4; ++r) acc[i][j][r] = 0.f;

  for (int k0 = 0; k0 < Kd; k0 += 32) {
    __syncthreads();
#pragma unroll
    for (int i = 0; i < 2; ++i) {
      const int c = w * 128 + i * 64 + l;       // 16B chunk id, 0..511
      const int r = c >> 2, cc = c & 3;         // tile row, 8-elem col chunk
      gload_lds16(A + (size_t)(rowBase + r) * Kd + k0 + cc * 8,
                  (void*)&As[(w * 128 + i * 64) * 8]);
      gload_lds16(Bt + (size_t)(colBase + r) * Kd + k0 + cc * 8,
                  (void*)&Bs[(w * 128 + i * 64) * 8]);
    }
    __syncthreads();
    short8 af[4], bfr[4];
#pragma unroll
    for (int fm = 0; fm < 4; ++fm)
      af[fm] = *reinterpret_cast<const short8*>(
          &As[(wr * 64 + fm * 16 + l15) * 32 + lg * 8]);
#pragma unroll
    for (int fn = 0; fn < 4; ++fn)
      bfr[fn] = *reinterpret_cast<const short8*>(
          &Bs[(wc * 64 + fn * 16 + l15) * 32 + lg * 8]);
#pragma unroll
    for (int fm = 0; fm < 4; ++fm)
#pragma unroll
      for (int fn = 0; fn < 4; ++fn)
        acc[fm][fn] = __builtin_amdgcn_mfma_f32_16x16x32_bf16(
            af[fm], bfr[fn], acc[fm][fn], 0, 0, 0);
  }

  // epilogue: C row = rowBase+wr*64+fm*16+lg*4+fr ; col = colBase+wc*64+fn*16+l15
  const int mrow0 = rowBase + wr * 64;
  const int ncol0 = colBase + wc * 64;
#pragma unroll
  for (int fm = 0; fm < 4; ++fm) {
#pragma unroll
    for (int fn = 0; fn < 4; ++fn) {
      const int col = ncol0 + fn * 16 + l15;
#pragma unroll
      for (int fr = 0; fr < 4; ++fr) {
        const int row = mrow0 + fm * 16 + lg * 4 + fr;
        float v = acc[fm][fn][fr];
        if constexpr (EPI == 0) {
          const int which = col / CD;  // 0=q 1=k 2=v (block never straddles)
          const int hk = col - which * CD;
          const float* bias = (which == 0) ? bias0 : (which == 1) ? bias1 : bias2;
          v += (which == 0) ? bias[hk] * 0.125f : bias[hk];
          const int b = row >> 10, n = row & 1023;
          const int h = hk >> 6, kk = hk & 63;
          if (which == 2) {  // V transposed: [B,H,K,N]
            dst2[((size_t)(b * CH + h) * CK + kk) * CN + n] = __float2bfloat16(v);
          } else {
            bf16* dst = (which == 0) ? dst0 : dst1;
            dst[(((size_t)(b * CH + h)) * CN + n) * CK + kk] = __float2bfloat16(v);
          }
        } else if constexpr (EPI == 1) {
          v += bias0[col] + resid[(size_t)row * CD + col];
          outF[(size_t)row * CD + col] = v;
        } else {  // EPI == 2: exact GELU -> bf16, ld = CF
          v += bias0[col];
          const float gel = 0.5f * v * (1.0f + erff(v * 0.70710678118654752f));
          dst0[(size_t)row * CF + col] = __float2bfloat16(gel);
        }
      }
    }
  }
}

// ---------------------------------------------------------------- attention
// Streaming flash attention, ZERO barriers. grid = 96 heads x 8; block = 256
// (4 independent waves). Wave w owns 32 q-rows (two 16-row subtiles sharing
// K/V fragments). K/V fragments stream global->reg (L2-resident, 256KB/head).
// Swapped QK^T: S^T = mfma(K,Q) -> key axis lane-local (16 vals in-reg),
// softmax = 15 fmax + 2 shfl. Q pre-scaled by 1/8 (in wq/bq).
// Q,K: bf16 [B,H,N,64]; Vt: bf16 [B,H,64,N]; ctx out: bf16 [B,N,H*64].
__global__ __launch_bounds__(256, 3) void attn_kernel(
    const bf16* __restrict__ Qb, const bf16* __restrict__ Kb,
    const bf16* __restrict__ Vtb, bf16* __restrict__ ctxb) {
  __shared__ __align__(16) bf16 Ps[4][16][72];  // per-wave P tile [q][k]

  const int tid = threadIdx.x;
  const int w = tid >> 6, l = tid & 63;
  const int l15 = l & 15, lg = l >> 4;
  const int bh = blockIdx.x >> 3;   // head id 0..95
  const int qb = blockIdx.x & 7;    // 128-row q block
  const int b = bh / CH, h = bh - b * CH;
  const bf16* Qh  = Qb  + (size_t)bh * CN * CK;
  const bf16* Kh  = Kb  + (size_t)bh * CN * CK;
  const bf16* Vth = Vtb + (size_t)bh * CK * CN;
  const int q0 = qb * 128 + w * 32;

  // Q fragments held for the whole pass: aq[sub][half]
  short8 aq[2][2];
#pragma unroll
  for (int s = 0; s < 2; ++s)
#pragma unroll
    for (int c = 0; c < 2; ++c)
      aq[s][c] = *reinterpret_cast<const short8*>(
          Qh + (size_t)(q0 + s * 16 + l15) * CK + c * 32 + lg * 8);

  f32x4 oacc[2][4];
  float mreg[2], lsum[2];
#pragma unroll
  for (int s = 0; s < 2; ++s) {
    mreg[s] = -INFINITY;
    lsum[s] = 0.f;
#pragma unroll
    for (int kb = 0; kb < 4; ++kb)
#pragma unroll
      for (int r = 0; r < 4; ++r) oacc[s][kb][r] = 0.f;
  }

  for (int kt = 0; kt < 16; ++kt) {
    // stream K fragments: kf[mb] covers keys kt*64+mb*16..+15
    const bf16* kbase = Kh + (size_t)kt * 64 * CK;
    short8 kf[4][2];
#pragma unroll
    for (int mb = 0; mb < 4; ++mb)
#pragma unroll
      for (int c = 0; c < 2; ++c)
        kf[mb][c] = *reinterpret_cast<const short8*>(
            kbase + (size_t)(mb * 16 + l15) * CK + c * 32 + lg * 8);
    // stream Vt fragments: vf[kb] covers dims kb*16..+15, keys kt*64..+63
    const bf16* vbase = Vth + (size_t)kt * 64;
    short8 vf[4][2];
#pragma unroll
    for (int kb = 0; kb < 4; ++kb)
#pragma unroll
      for (int c = 0; c < 2; ++c)
        vf[kb][c] = *reinterpret_cast<const short8*>(
            vbase + (size_t)(kb * 16 + l15) * CN + c * 32 + lg * 8);

#pragma unroll
    for (int s = 0; s < 2; ++s) {
      // S^T[k][q]: lane holds k = mb*16+lg*4+r for q = q0+s*16+l15
      f32x4 sacc[4];
#pragma unroll
      for (int mb = 0; mb < 4; ++mb) {
        f32x4 z;
#pragma unroll
        for (int r = 0; r < 4; ++r) z[r] = 0.f;
        z = __builtin_amdgcn_mfma_f32_16x16x32_bf16(kf[mb][0], aq[s][0], z, 0, 0, 0);
        z = __builtin_amdgcn_mfma_f32_16x16x32_bf16(kf[mb][1], aq[s][1], z, 0, 0, 0);
        sacc[mb] = z;
      }
      // online softmax: 16 in-register values + 2 shuffles
      float mx = sacc[0][0];
#pragma unroll
      for (int mb = 0; mb < 4; ++mb)
#pragma unroll
        for (int r = 0; r < 4; ++r) mx = fmaxf(mx, sacc[mb][r]);
      mx = fmaxf(mx, __shfl_xor(mx, 16));
      mx = fmaxf(mx, __shfl_xor(mx, 32));
      const float mnew = fmaxf(mreg[s], mx);
      const float alpha = __expf(mreg[s] - mnew);
      mreg[s] = mnew;
      float rs = 0.f;
#pragma unroll
      for (int mb = 0; mb < 4; ++mb)
#pragma unroll
        for (int r = 0; r < 4; ++r) {
          const float p = __expf(sacc[mb][r] - mnew);
          sacc[mb][r] = p;
          rs += p;
        }
      rs += __shfl_xor(rs, 16);
      rs += __shfl_xor(rs, 32);
      lsum[s] = lsum[s] * alpha + rs;

      // P^T -> Ps[w] (per-wave, no barrier): lane writes 4 consecutive k as 8B
#pragma unroll
      for (int mb = 0; mb < 4; ++mb) {
        bf16 tmp[4];
#pragma unroll
        for (int r = 0; r < 4; ++r) tmp[r] = __float2bfloat16(sacc[mb][r]);
        *reinterpret_cast<uint2*>(&Ps[w][l15][mb * 16 + lg * 4]) =
            *reinterpret_cast<const uint2*>(tmp);
      }
      // A-frag for PV: P[q=l15][k = lg*8..]
      const short8 pa0 = *reinterpret_cast<const short8*>(&Ps[w][l15][lg * 8]);
      const short8 pa1 = *reinterpret_cast<const short8*>(&Ps[w][l15][32 + lg * 8]);

      // rescale: oacc q-index = lg*4+r -> fetch that q's alpha from lane lg*4+r
      float alr[4];
#pragma unroll
      for (int r = 0; r < 4; ++r) alr[r] = __shfl(alpha, lg * 4 + r);
#pragma unroll
      for (int kb = 0; kb < 4; ++kb) {
#pragma unroll
        for (int r = 0; r < 4; ++r) oacc[s][kb][r] *= alr[r];
        oacc[s][kb] = __builtin_amdgcn_mfma_f32_16x16x32_bf16(pa0, vf[kb][0],
                                                              oacc[s][kb], 0, 0, 0);
        oacc[s][kb] = __builtin_amdgcn_mfma_f32_16x16x32_bf16(pa1, vf[kb][1],
                                                              oacc[s][kb], 0, 0, 0);
      }
    }
  }

  // finalize: ctx[b][n=q][h*64+d], O[q=lg*4+r][d=kb*16+l15]
#pragma unroll
  for (int s = 0; s < 2; ++s) {
#pragma unroll
    for (int r = 0; r < 4; ++r) {
      const float inv = 1.f / __shfl(lsum[s], lg * 4 + r);
      const int n = q0 + s * 16 + lg * 4 + r;
      bf16* dst = ctxb + ((size_t)(b * CN + n)) * CD + h * CK;
#pragma unroll
      for (int kb = 0; kb < 4; ++kb)
        dst[kb * 16 + l15] = __float2bfloat16(oacc[s][kb][r] * inv);
    }
  }
}

// ---------------------------------------------------------------- launcher
// ws arena (bytes):
//   0         wqkvt  bf16 [2304][768]
//   3538944   wot    bf16 [768][768]
//   4718592   w1t    bf16 [3072][768]
//   9437184   w2t    bf16 [768][3072]
//   14155776  h1     bf16 [8192][768]   } reused as g bf16 [8192][3072]
//   26738688  Q      bf16 [B,H,N,K]     }
//   39321600  K      bf16 [B,H,N,K]     }
//   51904512  Vt     bf16 [B,H,K,N]     }
//   64487424  ctx    bf16 [8192][768]   -> reused as h2
//   77070336  out    f32  [8192][768]
extern "C" void kernel_launch(void* const* d_in, const int* in_sizes, int n_in,
                              void* d_out, int out_size, void* d_ws,
                              size_t ws_size, hipStream_t stream) {
  const float* x    = (const float*)d_in[0];
  const float* ln1g = (const float*)d_in[1];
  const float* ln1b = (const float*)d_in[2];
  const float* wq   = (const float*)d_in[3];
  const float* bq   = (const float*)d_in[4];
  const float* wk   = (const float*)d_in[5];
  const float* bk   = (const float*)d_in[6];
  const float* wv   = (const float*)d_in[7];
  const float* bv   = (const float*)d_in[8];
  const float* wo   = (const float*)d_in[9];
  const float* bo   = (const float*)d_in[10];
  const float* ln2g = (const float*)d_in[11];
  const float* ln2b = (const float*)d_in[12];
  const float* w1   = (const float*)d_in[13];
  const float* b1   = (const float*)d_in[14];
  const float* w2   = (const float*)d_in[15];
  const float* b2   = (const float*)d_in[16];

  char* ws = (char*)d_ws;
  bf16* wqkvt = (bf16*)(ws + 0);
  bf16* wot   = (bf16*)(ws + 3538944);
  bf16* w1t   = (bf16*)(ws + 4718592);
  bf16* w2t   = (bf16*)(ws + 9437184);
  bf16* h1    = (bf16*)(ws + 14155776);
  bf16* Qbuf  = (bf16*)(ws + 26738688);
  bf16* Kbuf  = (bf16*)(ws + 39321600);
  bf16* Vtbuf = (bf16*)(ws + 51904512);
  bf16* gb    = (bf16*)(ws + 14155776);  // reuse h1+Q+K+V region
  bf16* ctxb  = (bf16*)(ws + 64487424);
  bf16* h2    = (bf16*)(ws + 64487424);  // reuse ctx region
  float* outb = (float*)(ws + 77070336);
  float* y    = (float*)d_out;

  // weight prep: fp32 [R][C] -> bf16 [C][R]; wq pre-scaled by 1/sqrt(K)=1/8
  transpose_f32_bf16<<<dim3(24, 24), 256, 0, stream>>>(wq, wqkvt, 768, 768, 0.125f);
  transpose_f32_bf16<<<dim3(24, 24), 256, 0, stream>>>(wk, wqkvt + 768 * 768, 768, 768, 1.f);
  transpose_f32_bf16<<<dim3(24, 24), 256, 0, stream>>>(wv, wqkvt + 2 * 768 * 768, 768, 768, 1.f);
  transpose_f32_bf16<<<dim3(24, 24), 256, 0, stream>>>(wo, wot, 768, 768, 1.f);
  transpose_f32_bf16<<<dim3(96, 24), 256, 0, stream>>>(w1, w1t, 768, 3072, 1.f);
  transpose_f32_bf16<<<dim3(24, 96), 256, 0, stream>>>(w2, w2t, 3072, 768, 1.f);

  ln_bf16<<<ROWS, 256, 0, stream>>>(x, ln1g, ln1b, h1);

  gemm_bf16_kernel<0><<<dim3(2304 / 128, ROWS / 128), 256, 0, stream>>>(
      h1, wqkvt, 768, nullptr, Qbuf, Kbuf, Vtbuf, bq, bk, bv, nullptr);

  attn_kernel<<<CB * CH * 8, 256, 0, stream>>>(Qbuf, Kbuf, Vtbuf, ctxb);

  gemm_bf16_kernel<1><<<dim3(768 / 128, ROWS / 128), 256, 0, stream>>>(
      ctxb, wot, 768, outb, nullptr, nullptr, nullptr, bo, nullptr, nullptr, x);

  ln_bf16<<<ROWS, 256, 0, stream>>>(outb, ln2g, ln2b, h2);

  gemm_bf16_kernel<2><<<dim3(3072 / 128, ROWS / 128), 256, 0, stream>>>(
      h2, w1t, 768, nullptr, gb, nullptr, nullptr, b1, nullptr, nullptr, nullptr);

  gemm_bf16_kernel<1><<<dim3(768 / 128, ROWS / 128), 256, 0, stream>>>(
      gb, w2t, 3072, y, nullptr, nullptr, nullptr, b2, nullptr, nullptr, outb);

  (void)in_sizes; (void)n_in; (void)out_size; (void)ws_size;
}